// Round 10
// baseline (225.421 us; speedup 1.0000x reference)
//
#include <hip/hip_runtime.h>

// ZeroUpsampling: out[b,c,2h,2w] = x[b,c,h,w], zeros elsewhere.
// x: (4,32,540,960) f32 -> out: (4,32,1080,1920) f32
//
// R9: R4's two-kernel traffic-class split REVISITED under R8's cache polarity
// (plain cacheable loads -> input stays L3-resident across graph replays;
// nontemporal stores -> 1.06 GB write stream doesn't displace it).
//   A) even rows: read float2 (L3 hit), store {v.x,0,v.y,0} dense nt float4.
//   B) odd rows:  pure nt zero fill (fill-class, ~6.9 TB/s).
// At HBM level both kernels are write-only (~531 MB each). R4 tested this
// split with nt loads (no retention) and it was neutral; retention changes
// the regime: A's reads no longer compete for HBM.
//
// Mapping per R2: t indexes (row r = t/480, quad oq = t%480); grid stride =
// exactly 1080 rows so oq is loop-invariant and the loop is pure pointer
// increments; exactly 64 iterations, no epilogue.

typedef float vfloat2 __attribute__((ext_vector_type(2)));
typedef float vfloat4 __attribute__((ext_vector_type(4)));

constexpr int W_IN  = 960;
constexpr int H_IN  = 540;
constexpr int BC    = 4 * 32;
constexpr int P2PR  = W_IN / 2;            // 480 float2 per input row
constexpr int OQPR  = (2 * W_IN) / 4;      // 480 float4 per output row
constexpr int ROWS  = BC * H_IN;           // 69120 flat input rows

constexpr int BLOCK = 256;
constexpr int GRID  = 2025;                // 2025*256 = 518400 = 480 * 1080
constexpr int STRIDE = GRID * BLOCK;
constexpr int ROWS_PER_ITER = STRIDE / P2PR;   // 1080
constexpr int ITERS = ROWS / ROWS_PER_ITER;    // 64, exact
constexpr size_t OUT_STEP = (size_t)ROWS_PER_ITER * 2 * OQPR; // float4 units

static_assert(STRIDE % P2PR == 0, "stride must be whole rows");
static_assert(ROWS % ROWS_PER_ITER == 0, "iteration count must be exact");

// Kernel A: even output rows. Reads hit L3 (plain loads); writes stream (nt).
__global__ __launch_bounds__(BLOCK)
void upsample_even_kernel(const vfloat2* __restrict__ in2, vfloat4* __restrict__ out) {
    const int t0 = blockIdx.x * BLOCK + threadIdx.x;
    const int r0 = t0 / P2PR;
    const int oq = t0 - r0 * P2PR;

    const vfloat2* ip  = in2 + t0;
    vfloat4*       ope = out + (size_t)(2 * r0) * OQPR + oq;

    #pragma unroll 4
    for (int i = 0; i < ITERS; ++i) {
        vfloat2 v = *ip;                           // plain cacheable load (L3-retain)
        vfloat4 e = {v.x, 0.f, v.y, 0.f};
        __builtin_nontemporal_store(e, ope);       // nt: don't pollute L3
        ip  += STRIDE;
        ope += OUT_STEP;
    }
}

// Kernel B: odd output rows, pure zero fill (write-only, fill-class).
__global__ __launch_bounds__(BLOCK)
void upsample_zero_kernel(vfloat4* __restrict__ out) {
    const int t0 = blockIdx.x * BLOCK + threadIdx.x;
    const int r0 = t0 / P2PR;
    const int oq = t0 - r0 * P2PR;

    vfloat4* opo = out + (size_t)(2 * r0 + 1) * OQPR + oq;
    const vfloat4 z = {0.f, 0.f, 0.f, 0.f};

    #pragma unroll 8
    for (int i = 0; i < ITERS; ++i) {
        __builtin_nontemporal_store(z, opo);
        opo += OUT_STEP;
    }
}

extern "C" void kernel_launch(void* const* d_in, const int* in_sizes, int n_in,
                              void* d_out, int out_size, void* d_ws, size_t ws_size,
                              hipStream_t stream) {
    const vfloat2* in2 = (const vfloat2*)d_in[0];
    vfloat4*       out = (vfloat4*)d_out;
    upsample_even_kernel<<<GRID, BLOCK, 0, stream>>>(in2, out);
    upsample_zero_kernel<<<GRID, BLOCK, 0, stream>>>(out);
}